// Round 6
// baseline (112.124 us; speedup 1.0000x reference)
//
#include <hip/hip_runtime.h>
#include <hip/hip_bf16.h>

#define NB      4096
#define ND      66
#define NSTEPP  1776                 // padded K/32 = 48*37 (true 1748)
#define KS      48                   // split-K chunks
#define CH      37                   // steps per chunk (exact)
#define MB      16                   // M blocks of 256 rows
#define FS      72                   // f row stride (halfs)

#define SBLK    NSTEPP               // 1776 prep blocks: woTi build
#define FBLK    (NB*FS/256)          // 1152 prep blocks: Fourier f
#define OBLK    (NB*ND/256)          // 1056 prep blocks: out = inputs

typedef __attribute__((ext_vector_type(8))) _Float16 f16x8;
typedef __attribute__((ext_vector_type(4))) float    f32x4;

// Static device scratch, fully rewritten every launch (deterministic).
__device__ __attribute__((aligned(16))) _Float16 g_f[NB * FS];
__device__ __attribute__((aligned(16))) _Float16 g_woTi[(size_t)(NSTEPP + 1) * 2048];

// bucket boundaries in octets (all % 4 == 0 -> cb wave-uniform per step)
__constant__ int c_bb[8] = {0, 48, 204, 532, 1096, 1960, 3188, 4844};

// descriptor for octet o: s0 | s1<<8 | cb<<16 ; value[j] = f[s0]*f[s1]*f[cb+j]
// s0==64 or s1==64 -> sentinel f==1 ; s0==65 -> pad (f==0)
__device__ inline unsigned octet_desc(int o) {
    int t = 0;
#pragma unroll
    for (int i = 1; i < 8; ++i) t += (o >= c_bb[i]);
    int li = o - c_bb[t];
    int P = 8 * t + 8, T = P * (P + 1) / 2;
    int s0, s1;
    if (li == 0)       { s0 = 64; s1 = 64; }
    else if (li <= P)  { s0 = li - 1; s1 = 64; }
    else if (li <= P + T) {
        int r = li - P - 1, a = 0;
        while (r >= P - a) { r -= P - a; ++a; }
        s0 = a; s1 = a + r;
    } else             { s0 = 65; s1 = 65; }
    return (unsigned)s0 | ((unsigned)s1 << 8) | ((unsigned)(8 * t) << 16);
}

// Fused prep: [0,SBLK) woTi ; [SBLK,SBLK+FBLK) Fourier f ; rest: out = inputs
__global__ void k_prep(const float* __restrict__ inp, const float* __restrict__ fw1,
                       const float* __restrict__ fw2, const float* __restrict__ fb1,
                       const float* __restrict__ wo, float* __restrict__ out) {
    const int bid = blockIdx.x, tid = threadIdx.x;
    if (bid < SBLK) {
        __shared__ unsigned sd[4];
        if (tid < 4) sd[tid] = octet_desc(bid * 4 + tid);
        __syncthreads();
        const int q = tid >> 6, gg = (tid >> 4) & 3, rl = tid & 15;
        const unsigned d = sd[gg];
        const int s0 = d & 255, s1 = (d >> 8) & 255, cb = d >> 16;
        const int n = q * 16 + rl;
        f16x8 v;
        if (s0 == 64) {                              // single: f[cb+j]
#pragma unroll
            for (int j = 0; j < 8; ++j) v[j] = (_Float16)wo[(cb + j) * 64 + n];
        } else if (s0 < 64 && s1 == 64) {            // pair (a=s0, b=cb+j)
            int base = 64 + s0 * (129 - s0) / 2 + (cb - s0);
#pragma unroll
            for (int j = 0; j < 8; ++j)
                v[j] = (cb + j >= s0) ? (_Float16)wo[(base + j) * 64 + n] : (_Float16)0.f;
        } else if (s0 < 64) {                        // triple (a=s0, b=s1, c=cb+j)
            int a = s0, b = s1;
            int TP = 45760 - (64 - a) * (65 - a) * (66 - a) / 6;
            int RB = b * (129 - b) / 2 - a * (129 - a) / 2;
            int base = 2144 + TP + RB + (cb - b);
#pragma unroll
            for (int j = 0; j < 8; ++j)
                v[j] = (cb + j >= b) ? (_Float16)wo[(base + j) * 64 + n] : (_Float16)0.f;
        } else {                                     // pad
#pragma unroll
            for (int j = 0; j < 8; ++j) v[j] = (_Float16)0.f;
        }
        *(f16x8*)(g_woTi + (size_t)bid * 2048 + tid * 8) = v;
    } else if (bid < SBLK + FBLK) {
        int i = (bid - SBLK) * 256 + tid;            // NB*FS exact
        int r = i / FS, c = i - r * FS;
        float v;
        if (c < 64)       v = cosf(inp[r * ND + c] * fw1[c] + fb1[c]) * fw2[c];
        else if (c == 64) v = 1.0f;
        else              v = 0.0f;
        g_f[i] = (_Float16)v;
    } else {
        int i = (bid - SBLK - FBLK) * 256 + tid;     // NB*ND exact
        out[i] = inp[i];
    }
}

__global__ __launch_bounds__(256, 3) void k_gemm(float* __restrict__ out) {
    __shared__ __attribute__((aligned(16))) _Float16 fl[256 * FS];
    __shared__ __attribute__((aligned(16))) unsigned ldescT[4 * 40];
    const int mb = blockIdx.x, ks = blockIdx.y, tid = threadIdx.x;
    const int s0c = ks * CH;

    {   // stage f tile (256 rows) + transposed per-g descriptor rows
        const uint4* src = (const uint4*)(g_f + (size_t)mb * 256 * FS);
        uint4* dst = (uint4*)fl;
        for (int e = tid; e < 256 * FS * 2 / 16; e += 256) dst[e] = src[e];
        for (int e = tid; e < 160; e += 256) {
            int gg = e / 40, s = e - gg * 40;
            ldescT[e] = (s < CH) ? octet_desc((s0c + s) * 4 + gg) : (65u | (65u << 8));
        }
    }
    __syncthreads();

    const int wave = tid >> 6, lane = tid & 63, rl = lane & 15, g = lane >> 4;
    const _Float16* fr0 = fl + (wave * 64 +  0 + rl) * FS;
    const _Float16* fr1 = fl + (wave * 64 + 16 + rl) * FS;
    const _Float16* fr2 = fl + (wave * 64 + 32 + rl) * FS;
    const _Float16* fr3 = fl + (wave * 64 + 48 + rl) * FS;

    f32x4 acc[4][4];
#pragma unroll
    for (int a = 0; a < 4; ++a)
#pragma unroll
        for (int q = 0; q < 4; ++q) acc[a][q] = f32x4{0.f, 0.f, 0.f, 0.f};

    f16x8 c0{}, c1{}, c2{}, c3{};
    _Float16 fa0 = 0, fa1 = 0, fa2 = 0, fa3 = 0;
    int cbPrev = -1, siPrev = -1;

    const _Float16* bptr = g_woTi + (size_t)s0c * 2048 + lane * 8;
    f16x8 B0 = *(const f16x8*)(bptr +    0);
    f16x8 B1 = *(const f16x8*)(bptr +  512);
    f16x8 B2 = *(const f16x8*)(bptr + 1024);
    f16x8 B3 = *(const f16x8*)(bptr + 1536);
    bptr += 2048;

#define STEP(dv)                                                               \
    {                                                                          \
        const int si0 = (dv) & 255, si1 = ((dv) >> 8) & 255;                   \
        const int cb = __builtin_amdgcn_readfirstlane((dv) >> 16);             \
        if (__any(si0 != siPrev)) {                                            \
            siPrev = si0;                                                      \
            fa0 = fr0[si0]; fa1 = fr1[si0]; fa2 = fr2[si0]; fa3 = fr3[si0];    \
        }                                                                      \
        if (cb != cbPrev) {                                                    \
            cbPrev = cb;                                                       \
            c0 = *(const f16x8*)(fr0 + cb); c1 = *(const f16x8*)(fr1 + cb);    \
            c2 = *(const f16x8*)(fr2 + cb); c3 = *(const f16x8*)(fr3 + cb);    \
        }                                                                      \
        f16x8 nB0 = *(const f16x8*)(bptr +    0);                              \
        f16x8 nB1 = *(const f16x8*)(bptr +  512);                              \
        f16x8 nB2 = *(const f16x8*)(bptr + 1024);                              \
        f16x8 nB3 = *(const f16x8*)(bptr + 1536);                              \
        bptr += 2048;                                                          \
        const _Float16 p0 = fa0 * fr0[si1], p1 = fa1 * fr1[si1];               \
        const _Float16 p2 = fa2 * fr2[si1], p3 = fa3 * fr3[si1];               \
        const f16x8 a0 = c0 * p0, a1 = c1 * p1, a2 = c2 * p2, a3 = c3 * p3;    \
        acc[0][0] = __builtin_amdgcn_mfma_f32_16x16x32_f16(a0, B0, acc[0][0], 0, 0, 0); \
        acc[0][1] = __builtin_amdgcn_mfma_f32_16x16x32_f16(a0, B1, acc[0][1], 0, 0, 0); \
        acc[0][2] = __builtin_amdgcn_mfma_f32_16x16x32_f16(a0, B2, acc[0][2], 0, 0, 0); \
        acc[0][3] = __builtin_amdgcn_mfma_f32_16x16x32_f16(a0, B3, acc[0][3], 0, 0, 0); \
        acc[1][0] = __builtin_amdgcn_mfma_f32_16x16x32_f16(a1, B0, acc[1][0], 0, 0, 0); \
        acc[1][1] = __builtin_amdgcn_mfma_f32_16x16x32_f16(a1, B1, acc[1][1], 0, 0, 0); \
        acc[1][2] = __builtin_amdgcn_mfma_f32_16x16x32_f16(a1, B2, acc[1][2], 0, 0, 0); \
        acc[1][3] = __builtin_amdgcn_mfma_f32_16x16x32_f16(a1, B3, acc[1][3], 0, 0, 0); \
        acc[2][0] = __builtin_amdgcn_mfma_f32_16x16x32_f16(a2, B0, acc[2][0], 0, 0, 0); \
        acc[2][1] = __builtin_amdgcn_mfma_f32_16x16x32_f16(a2, B1, acc[2][1], 0, 0, 0); \
        acc[2][2] = __builtin_amdgcn_mfma_f32_16x16x32_f16(a2, B2, acc[2][2], 0, 0, 0); \
        acc[2][3] = __builtin_amdgcn_mfma_f32_16x16x32_f16(a2, B3, acc[2][3], 0, 0, 0); \
        acc[3][0] = __builtin_amdgcn_mfma_f32_16x16x32_f16(a3, B0, acc[3][0], 0, 0, 0); \
        acc[3][1] = __builtin_amdgcn_mfma_f32_16x16x32_f16(a3, B1, acc[3][1], 0, 0, 0); \
        acc[3][2] = __builtin_amdgcn_mfma_f32_16x16x32_f16(a3, B2, acc[3][2], 0, 0, 0); \
        acc[3][3] = __builtin_amdgcn_mfma_f32_16x16x32_f16(a3, B3, acc[3][3], 0, 0, 0); \
        B0 = nB0; B1 = nB1; B2 = nB2; B3 = nB3;                                \
    }

    const unsigned* dT = ldescT + g * 40;
    for (int s2 = 0; s2 < 36; s2 += 2) {         // 18 iters x 2 steps
        uint2 dd = *(const uint2*)(dT + s2);     // broadcast 8B LDS read
        STEP(dd.x);
        STEP(dd.y);
    }
    STEP(dT[36]);                                // tail step (CH = 37)
#undef STEP

    // atomic f32 epilogue into out (init'd to inputs by k_prep)
    const int rbase = mb * 256 + wave * 64 + g * 4;
#pragma unroll
    for (int aa = 0; aa < 4; ++aa)
#pragma unroll
        for (int q = 0; q < 4; ++q)
#pragma unroll
            for (int i2 = 0; i2 < 4; ++i2)
                atomicAdd(&out[(size_t)(rbase + aa * 16 + i2) * ND + q * 16 + rl],
                          acc[aa][q][i2]);
}

extern "C" void kernel_launch(void* const* d_in, const int* in_sizes, int n_in,
                              void* d_out, int out_size, void* d_ws, size_t ws_size,
                              hipStream_t stream) {
    const float* inp = (const float*)d_in[0];
    const float* fw1 = (const float*)d_in[1];
    const float* fw2 = (const float*)d_in[2];
    const float* fb1 = (const float*)d_in[3];
    const float* wo  = (const float*)d_in[4];
    float* out = (float*)d_out;

    k_prep<<<SBLK + FBLK + OBLK, 256, 0, stream>>>(inp, fw1, fw2, fb1, wo, out);
    k_gemm<<<dim3(MB, KS), 256, 0, stream>>>(out);
}

// Round 7
// 48.845 us; speedup vs baseline: 2.2955x; 2.2955x over previous
//
#include <hip/hip_runtime.h>
#include <hip/hip_bf16.h>

#define NB      4096
#define ND      66
#define NSTEPP  1792                 // padded K/32 = 64*28 (true 1748)
#define KS      64                   // split-K chunks
#define CH      28                   // steps per chunk (exact, even)
#define MB      16                   // M blocks of 256 rows
#define FS      72                   // f row stride (halfs)

#define SBLK    NSTEPP               // 1792 prep blocks: woTi build
#define FBLK    (NB*FS/256)          // 1152 prep blocks: Fourier f
#define OBLK    (NB*ND/256)          // 1056 prep blocks: out = inputs

typedef __attribute__((ext_vector_type(8))) _Float16 f16x8;
typedef __attribute__((ext_vector_type(4))) _Float16 f16x4;
typedef __attribute__((ext_vector_type(4))) float    f32x4;

// Static device scratch, fully rewritten every launch (deterministic).
__device__ __attribute__((aligned(16))) _Float16 g_f[NB * FS];
__device__ __attribute__((aligned(16))) _Float16 g_woTi[(size_t)(NSTEPP + 1) * 2048];
__device__ __attribute__((aligned(16))) _Float16 g_part[(size_t)KS * MB * 4 * 16 * 256];

// bucket boundaries in octets (all % 4 == 0 -> cb wave-uniform per step)
__constant__ int c_bb[8] = {0, 48, 204, 532, 1096, 1960, 3188, 4844};

// descriptor for octet o: s0 | s1<<8 | cb<<16 ; value[j] = f[s0]*f[s1]*f[cb+j]
// s0==64 or s1==64 -> sentinel f==1 ; s0==65 -> pad (f==0)
__device__ inline unsigned octet_desc(int o) {
    int t = 0;
#pragma unroll
    for (int i = 1; i < 8; ++i) t += (o >= c_bb[i]);
    int li = o - c_bb[t];
    int P = 8 * t + 8, T = P * (P + 1) / 2;
    int s0, s1;
    if (li == 0)       { s0 = 64; s1 = 64; }
    else if (li <= P)  { s0 = li - 1; s1 = 64; }
    else if (li <= P + T) {
        int r = li - P - 1, a = 0;
        while (r >= P - a) { r -= P - a; ++a; }
        s0 = a; s1 = a + r;
    } else             { s0 = 65; s1 = 65; }
    return (unsigned)s0 | ((unsigned)s1 << 8) | ((unsigned)(8 * t) << 16);
}

// Fused prep: [0,SBLK) woTi ; [SBLK,SBLK+FBLK) Fourier f ; rest: out = inputs
__global__ void k_prep(const float* __restrict__ inp, const float* __restrict__ fw1,
                       const float* __restrict__ fw2, const float* __restrict__ fb1,
                       const float* __restrict__ wo, float* __restrict__ out) {
    const int bid = blockIdx.x, tid = threadIdx.x;
    if (bid < SBLK) {
        __shared__ unsigned sd[4];
        if (tid < 4) sd[tid] = octet_desc(bid * 4 + tid);
        __syncthreads();
        const int q = tid >> 6, gg = (tid >> 4) & 3, rl = tid & 15;
        const unsigned d = sd[gg];
        const int s0 = d & 255, s1 = (d >> 8) & 255, cb = d >> 16;
        const int n = q * 16 + rl;
        f16x8 v;
        if (s0 == 64) {                              // single: f[cb+j]
#pragma unroll
            for (int j = 0; j < 8; ++j) v[j] = (_Float16)wo[(cb + j) * 64 + n];
        } else if (s0 < 64 && s1 == 64) {            // pair (a=s0, b=cb+j)
            int base = 64 + s0 * (129 - s0) / 2 + (cb - s0);
#pragma unroll
            for (int j = 0; j < 8; ++j)
                v[j] = (cb + j >= s0) ? (_Float16)wo[(base + j) * 64 + n] : (_Float16)0.f;
        } else if (s0 < 64) {                        // triple (a=s0, b=s1, c=cb+j)
            int a = s0, b = s1;
            int TP = 45760 - (64 - a) * (65 - a) * (66 - a) / 6;
            int RB = b * (129 - b) / 2 - a * (129 - a) / 2;
            int base = 2144 + TP + RB + (cb - b);
#pragma unroll
            for (int j = 0; j < 8; ++j)
                v[j] = (cb + j >= b) ? (_Float16)wo[(base + j) * 64 + n] : (_Float16)0.f;
        } else {                                     // pad
#pragma unroll
            for (int j = 0; j < 8; ++j) v[j] = (_Float16)0.f;
        }
        *(f16x8*)(g_woTi + (size_t)bid * 2048 + tid * 8) = v;
    } else if (bid < SBLK + FBLK) {
        int i = (bid - SBLK) * 256 + tid;            // NB*FS exact
        int r = i / FS, c = i - r * FS;
        float v;
        if (c < 64)       v = cosf(inp[r * ND + c] * fw1[c] + fb1[c]) * fw2[c];
        else if (c == 64) v = 1.0f;
        else              v = 0.0f;
        g_f[i] = (_Float16)v;
    } else {
        int i = (bid - SBLK - FBLK) * 256 + tid;     // NB*ND exact
        out[i] = inp[i];
    }
}

__global__ __launch_bounds__(256, 4) void k_gemm() {
    __shared__ __attribute__((aligned(16))) _Float16 fl[256 * FS];
    __shared__ __attribute__((aligned(16))) unsigned ldescT[4 * 32];
    const int mb = blockIdx.x, ks = blockIdx.y, tid = threadIdx.x;
    const int s0c = ks * CH;

    {   // stage f tile (256 rows) + transposed per-g descriptor rows
        const uint4* src = (const uint4*)(g_f + (size_t)mb * 256 * FS);
        uint4* dst = (uint4*)fl;
        for (int e = tid; e < 256 * FS * 2 / 16; e += 256) dst[e] = src[e];
        if (tid < 128) {
            int gg = tid >> 5, s = tid & 31;
            ldescT[tid] = (s < CH) ? octet_desc((s0c + s) * 4 + gg) : (65u | (65u << 8));
        }
    }
    __syncthreads();

    const int wave = tid >> 6, lane = tid & 63, rl = lane & 15, g = lane >> 4;
    const _Float16* fr0 = fl + (wave * 64 +  0 + rl) * FS;
    const _Float16* fr1 = fl + (wave * 64 + 16 + rl) * FS;
    const _Float16* fr2 = fl + (wave * 64 + 32 + rl) * FS;
    const _Float16* fr3 = fl + (wave * 64 + 48 + rl) * FS;

    f32x4 acc[4][4];
#pragma unroll
    for (int a = 0; a < 4; ++a)
#pragma unroll
        for (int q = 0; q < 4; ++q) acc[a][q] = f32x4{0.f, 0.f, 0.f, 0.f};

    f16x8 c0{}, c1{}, c2{}, c3{};
    _Float16 fa0 = 0, fa1 = 0, fa2 = 0, fa3 = 0;
    int cbPrev = -1, siPrev = -1;

    const _Float16* bptr = g_woTi + (size_t)s0c * 2048 + lane * 8;
    f16x8 B0 = *(const f16x8*)(bptr +    0);
    f16x8 B1 = *(const f16x8*)(bptr +  512);
    f16x8 B2 = *(const f16x8*)(bptr + 1024);
    f16x8 B3 = *(const f16x8*)(bptr + 1536);
    bptr += 2048;

#define STEP(dv)                                                               \
    {                                                                          \
        const int si0 = (dv) & 255, si1 = ((dv) >> 8) & 255;                   \
        const int cb = __builtin_amdgcn_readfirstlane((dv) >> 16);             \
        if (__any(si0 != siPrev)) {                                            \
            siPrev = si0;                                                      \
            fa0 = fr0[si0]; fa1 = fr1[si0]; fa2 = fr2[si0]; fa3 = fr3[si0];    \
        }                                                                      \
        if (cb != cbPrev) {                                                    \
            cbPrev = cb;                                                       \
            c0 = *(const f16x8*)(fr0 + cb); c1 = *(const f16x8*)(fr1 + cb);    \
            c2 = *(const f16x8*)(fr2 + cb); c3 = *(const f16x8*)(fr3 + cb);    \
        }                                                                      \
        f16x8 nB0 = *(const f16x8*)(bptr +    0);                              \
        f16x8 nB1 = *(const f16x8*)(bptr +  512);                              \
        f16x8 nB2 = *(const f16x8*)(bptr + 1024);                              \
        f16x8 nB3 = *(const f16x8*)(bptr + 1536);                              \
        bptr += 2048;                                                          \
        const _Float16 p0 = fa0 * fr0[si1], p1 = fa1 * fr1[si1];               \
        const _Float16 p2 = fa2 * fr2[si1], p3 = fa3 * fr3[si1];               \
        const f16x8 a0 = c0 * p0, a1 = c1 * p1, a2 = c2 * p2, a3 = c3 * p3;    \
        acc[0][0] = __builtin_amdgcn_mfma_f32_16x16x32_f16(a0, B0, acc[0][0], 0, 0, 0); \
        acc[0][1] = __builtin_amdgcn_mfma_f32_16x16x32_f16(a0, B1, acc[0][1], 0, 0, 0); \
        acc[0][2] = __builtin_amdgcn_mfma_f32_16x16x32_f16(a0, B2, acc[0][2], 0, 0, 0); \
        acc[0][3] = __builtin_amdgcn_mfma_f32_16x16x32_f16(a0, B3, acc[0][3], 0, 0, 0); \
        acc[1][0] = __builtin_amdgcn_mfma_f32_16x16x32_f16(a1, B0, acc[1][0], 0, 0, 0); \
        acc[1][1] = __builtin_amdgcn_mfma_f32_16x16x32_f16(a1, B1, acc[1][1], 0, 0, 0); \
        acc[1][2] = __builtin_amdgcn_mfma_f32_16x16x32_f16(a1, B2, acc[1][2], 0, 0, 0); \
        acc[1][3] = __builtin_amdgcn_mfma_f32_16x16x32_f16(a1, B3, acc[1][3], 0, 0, 0); \
        acc[2][0] = __builtin_amdgcn_mfma_f32_16x16x32_f16(a2, B0, acc[2][0], 0, 0, 0); \
        acc[2][1] = __builtin_amdgcn_mfma_f32_16x16x32_f16(a2, B1, acc[2][1], 0, 0, 0); \
        acc[2][2] = __builtin_amdgcn_mfma_f32_16x16x32_f16(a2, B2, acc[2][2], 0, 0, 0); \
        acc[2][3] = __builtin_amdgcn_mfma_f32_16x16x32_f16(a2, B3, acc[2][3], 0, 0, 0); \
        acc[3][0] = __builtin_amdgcn_mfma_f32_16x16x32_f16(a3, B0, acc[3][0], 0, 0, 0); \
        acc[3][1] = __builtin_amdgcn_mfma_f32_16x16x32_f16(a3, B1, acc[3][1], 0, 0, 0); \
        acc[3][2] = __builtin_amdgcn_mfma_f32_16x16x32_f16(a3, B2, acc[3][2], 0, 0, 0); \
        acc[3][3] = __builtin_amdgcn_mfma_f32_16x16x32_f16(a3, B3, acc[3][3], 0, 0, 0); \
        B0 = nB0; B1 = nB1; B2 = nB2; B3 = nB3;                                \
    }

    const unsigned* dT = ldescT + g * 32;
    for (int s2 = 0; s2 < CH; s2 += 2) {         // 14 iters x 2 steps, no tail
        uint2 dd = *(const uint2*)(dT + s2);     // broadcast 8B LDS read
        STEP(dd.x);
        STEP(dd.y);
    }
#undef STEP

    // fp16 partials, layout [ks][mb][wave][a][q][lane][i2] — 8B vector store/lane
    _Float16* pp = g_part + ((((size_t)ks * MB + mb) * 4 + wave) * 16) * 256;
#pragma unroll
    for (int a = 0; a < 4; ++a)
#pragma unroll
        for (int q = 0; q < 4; ++q) {
            f16x4 v;
            v[0] = (_Float16)acc[a][q][0]; v[1] = (_Float16)acc[a][q][1];
            v[2] = (_Float16)acc[a][q][2]; v[3] = (_Float16)acc[a][q][3];
            *(f16x4*)(pp + (a * 4 + q) * 256 + lane * 4) = v;
        }
}

// out[:, :64] = inputs + sum_ks partials
__global__ void k_reduce(const float* __restrict__ inp, float* __restrict__ out) {
    int t = blockIdx.x * 256 + threadIdx.x;          // 65536 threads
    int c = t & 63, rg = t >> 6;
    int mb = rg >> 6, wave = (rg >> 4) & 3, a = (rg >> 2) & 3, g = rg & 3;
    int q = c >> 4, rl = c & 15, lane = g * 16 + rl;
    int rbase = mb * 256 + wave * 64 + a * 16 + g * 4;
    float acc[4];
#pragma unroll
    for (int i2 = 0; i2 < 4; ++i2) acc[i2] = inp[(rbase + i2) * ND + c];
    const _Float16* pp = g_part + ((((size_t)mb * 4 + wave) * 16) + a * 4 + q) * 256 + lane * 4;
#pragma unroll
    for (int ks = 0; ks < KS; ++ks) {
        const f16x4 p = *(const f16x4*)(pp + (size_t)ks * MB * 4 * 16 * 256);
#pragma unroll
        for (int i2 = 0; i2 < 4; ++i2) acc[i2] += (float)p[i2];
    }
#pragma unroll
    for (int i2 = 0; i2 < 4; ++i2) out[(rbase + i2) * ND + c] = acc[i2];
}

extern "C" void kernel_launch(void* const* d_in, const int* in_sizes, int n_in,
                              void* d_out, int out_size, void* d_ws, size_t ws_size,
                              hipStream_t stream) {
    const float* inp = (const float*)d_in[0];
    const float* fw1 = (const float*)d_in[1];
    const float* fw2 = (const float*)d_in[2];
    const float* fb1 = (const float*)d_in[3];
    const float* wo  = (const float*)d_in[4];
    float* out = (float*)d_out;

    k_prep<<<SBLK + FBLK + OBLK, 256, 0, stream>>>(inp, fw1, fw2, fb1, wo, out);
    k_gemm<<<dim3(MB, KS), 256, 0, stream>>>();
    k_reduce<<<256, 256, 0, stream>>>(inp, out);
}